// Round 6
// baseline (208.990 us; speedup 1.0000x reference)
//
#include <hip/hip_runtime.h>

// ---------------------------------------------------------------------------
// FactorizedSynthesizerRandom: B=8, S=2048, D=1024, K=8
//   q = x@Wq+bq, k = x@Wk+bk  (rank-8)
//   attn = softmax(q k^T)                        -> output[1] (f32, 8x2048x2048)
//   out  = attn @ (x@Wv+bv)                      -> output[0] (f32, 8x2048x1024)
// Round 6: 2-blocks/CU GEMM. BM=256 BN=128 BK=32, 4 waves (128x64 each,
// preserves 42.7 FLOP/LDS-byte balance), 48KB LDS staging (2 slots x 24KB),
// counted vmcnt(6), 512-block grids (exactly 2/CU). gemm0 adds a swizzled
// LDS-transpose epilogue so vt writes are coalesced bf16x8 (was 8B-scattered).
// ---------------------------------------------------------------------------

typedef __attribute__((ext_vector_type(8))) __bf16 bf16x8;
typedef __attribute__((ext_vector_type(4))) __bf16 bf16x4;
typedef __attribute__((ext_vector_type(4))) float  f32x4;
typedef unsigned int u32;

#define GLB_CAST(p) ((const __attribute__((address_space(1))) u32*)(p))
#define LDS_CAST(p) ((__attribute__((address_space(3))) u32*)(p))

#define S_BARRIER() { __builtin_amdgcn_s_barrier(); __builtin_amdgcn_sched_barrier(0); }
#define VMCNT6()    { asm volatile("s_waitcnt vmcnt(6)" ::: "memory"); __builtin_amdgcn_sched_barrier(0); }
#define VMCNT0()    { asm volatile("s_waitcnt vmcnt(0)" ::: "memory"); __builtin_amdgcn_sched_barrier(0); }

static constexpr int    Bn   = 8;
static constexpr int    S    = 2048;
static constexpr int    Dd   = 1024;
static constexpr int    Mtot = Bn * S;            // 16384
static constexpr size_t OUT0 = (size_t)Bn * S * Dd;

// workspace layout (bytes)
static constexpr size_t OFF_XBF  = 0;                                  // [16384][1024] bf16
static constexpr size_t OFF_WVT  = OFF_XBF + (size_t)Mtot * Dd * 2;    // [1024][1024] bf16 (Wv^T)
static constexpr size_t OFF_Q    = OFF_WVT + (size_t)Dd * Dd * 2;      // [16384][8] f32
static constexpr size_t OFF_K    = OFF_Q   + (size_t)Mtot * 8 * 4;     // [16384][8] f32
static constexpr size_t OFF_VT   = OFF_K   + (size_t)Mtot * 8 * 4;     // [8][1024][2048] bf16
static constexpr size_t OFF_ATTB = OFF_VT  + (size_t)Bn * Dd * S * 2;  // [8][2048][2048] bf16
static constexpr size_t WS_NEED  = OFF_ATTB + (size_t)Bn * S * S * 2;  // ~131 MB

// ---------------------------------------------------------------------------
// prep: blocks [0,256): q/k projection straight from f32 x, Wq, Wk;
//       [256,512): Wv -> Wv^T bf16 ; [512,4608): x f32 -> bf16.
// ---------------------------------------------------------------------------
__global__ __launch_bounds__(256) void prep_kernel(
    const float* __restrict__ x, const float* __restrict__ Wq,
    const float* __restrict__ Wk, const float* __restrict__ Wv,
    const float* __restrict__ bq, const float* __restrict__ bk,
    __bf16* __restrict__ xbf, __bf16* __restrict__ wvt,
    float* __restrict__ qb, float* __restrict__ kb)
{
    __shared__ float lt[64][65];
    int bid = blockIdx.x, t = threadIdx.x;
    if (bid < 256) {
        int l = t & 63, w = t >> 6;
        int mbase = (bid * 4 + w) * 16;
        int n = l & 15;
        int dbase = (l >> 4) << 3;
        const float* xr = x + (size_t)(mbase + n) * 1024 + dbase;
        const float* wcol = (n < 8) ? (Wq + n) : (Wk + (n & 7));
        f32x4 acc = {0.f, 0.f, 0.f, 0.f};
        #pragma unroll 4
        for (int kk = 0; kk < 1024; kk += 32) {
            f32x4 a0 = *(const f32x4*)(xr + kk);
            f32x4 a1 = *(const f32x4*)(xr + kk + 4);
            bf16x8 a, b;
            #pragma unroll
            for (int c = 0; c < 4; ++c) { a[c] = (__bf16)a0[c]; a[4 + c] = (__bf16)a1[c]; }
            #pragma unroll
            for (int u = 0; u < 8; ++u) b[u] = (__bf16)wcol[(size_t)(dbase + kk + u) * 8];
            acc = __builtin_amdgcn_mfma_f32_16x16x32_bf16(a, b, acc, 0, 0, 0);
        }
        float bias = (n < 8) ? bq[n] : bk[n & 7];
        #pragma unroll
        for (int r = 0; r < 4; ++r) {
            int m = mbase + ((l >> 4) << 2) + r;
            float v = acc[r] + bias;
            if (n < 8) qb[m * 8 + n] = v;
            else       kb[m * 8 + (n & 7)] = v;
        }
    } else if (bid < 512) {
        int tile = bid - 256;
        int tr = tile >> 4, tc = tile & 15;
        int r0 = t >> 6, c = t & 63;
        #pragma unroll
        for (int i = 0; i < 16; ++i) {
            int row = i * 4 + r0;
            lt[row][c] = Wv[(size_t)(tr * 64 + row) * 1024 + tc * 64 + c];
        }
        __syncthreads();
        #pragma unroll
        for (int i = 0; i < 16; ++i) {
            int er = i * 4 + r0;
            wvt[(size_t)(tc * 64 + er) * 1024 + tr * 64 + c] = (__bf16)lt[c][er];
        }
    } else {
        int bid2 = bid - 512;
        #pragma unroll
        for (int i = 0; i < 4; ++i) {
            size_t idx4 = (size_t)i * 1048576 + (size_t)bid2 * 256 + t;
            f32x4 v = ((const f32x4*)x)[idx4];
            bf16x4 o;
            #pragma unroll
            for (int c = 0; c < 4; ++c) o[c] = (__bf16)v[c];
            ((bf16x4*)xbf)[idx4] = o;
        }
    }
}

// ---------------------------------------------------------------------------
// softmax: thread t owns cols j = t*8..t*8+7, k-slice in registers.
// Writes attn f32 (d_out) and attn bf16 (ws, PV GEMM input).
// ---------------------------------------------------------------------------
__global__ __launch_bounds__(256) void softmax_kernel(
    const float* __restrict__ qb, const float* __restrict__ kb,
    float* __restrict__ attnF, __bf16* __restrict__ attnB)
{
    int bid = blockIdx.x;
    int b = bid >> 6, chunk = bid & 63;
    int t = threadIdx.x, l = t & 63, w = t >> 6;
    float kr[8][8];
    const float* kbb = kb + ((size_t)b << 14);
    #pragma unroll
    for (int jj = 0; jj < 8; ++jj) {
        f32x4 v0 = *(const f32x4*)(kbb + (size_t)(t * 8 + jj) * 8);
        f32x4 v1 = *(const f32x4*)(kbb + (size_t)(t * 8 + jj) * 8 + 4);
        #pragma unroll
        for (int c = 0; c < 4; ++c) { kr[jj][c] = v0[c]; kr[jj][4 + c] = v1[c]; }
    }
    __shared__ float redm[4], reds[4];
    const float* qrow = qb + ((size_t)b << 14);
    for (int ii = 0; ii < 32; ++ii) {
        int i = (chunk << 5) + ii;
        f32x4 q0 = *(const f32x4*)(qrow + (size_t)i * 8);
        f32x4 q1 = *(const f32x4*)(qrow + (size_t)i * 8 + 4);
        float e[8];
        #pragma unroll
        for (int jj = 0; jj < 8; ++jj) {
            float s = q0[0] * kr[jj][0];
            s = fmaf(q0[1], kr[jj][1], s);
            s = fmaf(q0[2], kr[jj][2], s);
            s = fmaf(q0[3], kr[jj][3], s);
            s = fmaf(q1[0], kr[jj][4], s);
            s = fmaf(q1[1], kr[jj][5], s);
            s = fmaf(q1[2], kr[jj][6], s);
            s = fmaf(q1[3], kr[jj][7], s);
            e[jj] = s;
        }
        float mx = e[0];
        #pragma unroll
        for (int jj = 1; jj < 8; ++jj) mx = fmaxf(mx, e[jj]);
        #pragma unroll
        for (int d = 1; d < 64; d <<= 1) mx = fmaxf(mx, __shfl_xor(mx, d));
        if (l == 0) redm[w] = mx;
        __syncthreads();
        mx = fmaxf(fmaxf(redm[0], redm[1]), fmaxf(redm[2], redm[3]));
        float p[8], sum = 0.f;
        #pragma unroll
        for (int jj = 0; jj < 8; ++jj) { p[jj] = __expf(e[jj] - mx); sum += p[jj]; }
        #pragma unroll
        for (int d = 1; d < 64; d <<= 1) sum += __shfl_xor(sum, d);
        if (l == 0) reds[w] = sum;
        __syncthreads();
        float T = (reds[0] + reds[1]) + (reds[2] + reds[3]);
        float inv = 1.0f / T;
        size_t off = (((size_t)b << 11) + i) * 2048 + (size_t)t * 8;
        f32x4 o0, o1; bf16x8 ob;
        #pragma unroll
        for (int c = 0; c < 4; ++c) {
            o0[c] = p[c] * inv; o1[c] = p[4 + c] * inv;
            ob[c] = (__bf16)o0[c]; ob[4 + c] = (__bf16)o1[c];
        }
        *(f32x4*)(attnF + off) = o0;
        *(f32x4*)(attnF + off + 4) = o1;
        *(bf16x8*)(attnB + off) = ob;
    }
}

// ---------------------------------------------------------------------------
// GEMM: C[256x128] = A[M][Kz] * Bt[N][Kz]^T (bf16 row-major, stride Kz).
// 256 thr = 4 waves (2M x 2N), 128x64 out/wave (42.7 FLOP/LDS-byte), BK=32.
// LDS: 2 slots x (A 16KB + B 8KB) = 48KB -> 2 blocks/CU. 16B-slot swizzle
// slot ^= (row>>1)&3 (2-way banks, free) via pre-swizzled global source.
// Loop: reads+MFMA -> barrier -> stage(t+2) -> vmcnt(6) -> barrier.
// MODE 0: vt = (x@Wv+bv)^T bf16 [b][e][s], coalesced via LDS transpose (64KB)
// MODE 1: out = attn @ value f32 [b][i][e]
// ---------------------------------------------------------------------------
template<int MODE>
__global__ __launch_bounds__(256, 2) void gemm_kernel(
    const __bf16* __restrict__ A, const __bf16* __restrict__ Bt,
    float* __restrict__ outF, __bf16* __restrict__ outVt,
    const float* __restrict__ bv)
{
    constexpr int LDA = (MODE == 0) ? 1024 : 2048;
    constexpr int NT  = LDA / 32;
    __shared__ __align__(1024) char smem[(MODE == 0) ? 65536 : 49152];

    int bid = blockIdx.x;
    int wg = ((bid & 7) << 6) | (bid >> 3);     // bijective XCD swizzle (nwg=512)
    int t = threadIdx.x, l = t & 63;
    int wid = t >> 6;
    int wmr = wid >> 1, wnc = wid & 1;          // wave grid 2(M) x 2(N)

    int mblk, nblk, bb = 0;
    size_t aoff, boff;
    if constexpr (MODE == 0) {
        mblk = wg >> 3; nblk = wg & 7;          // 64 x 8
        aoff = (size_t)mblk * 256 * LDA;
        boff = (size_t)nblk * 128 * LDA;
    } else {
        bb = wg >> 6; int rr = wg & 63;         // one batch per XCD
        mblk = rr >> 3; nblk = rr & 7;          // 8 x 8
        aoff = (size_t)bb * S * S + (size_t)mblk * 256 * LDA;
        boff = (size_t)bb * Dd * S + (size_t)nblk * 128 * LDA;
    }

    // staging: pre-swizzled source slot; f(row) = (row>>1)&3 dep only on t bits
    int presw = (t & 3) ^ ((t >> 3) & 3);
    const __bf16* gA[4]; const __bf16* gB[2];
    #pragma unroll
    for (int c = 0; c < 4; ++c)
        gA[c] = A + aoff + (size_t)(c * 64 + (t >> 2)) * LDA + presw * 8;
    #pragma unroll
    for (int c = 0; c < 2; ++c)
        gB[c] = Bt + boff + (size_t)(c * 64 + (t >> 2)) * LDA + presw * 8;

    int lr = l & 15, lk = l >> 4;
    int fsl = (lk ^ ((lr >> 1) & 3)) << 3;       // lane-constant element slot
    int offA = (wmr * 128 + lr) * 32 + fsl;
    int offB = (wnc * 64 + lr) * 32 + fsl;

    f32x4 acc[8][4] = {};

    // prologue: stage tiles 0 (slot0), 1 (slot1); wait tile0.
    #pragma unroll
    for (int c = 0; c < 4; ++c)
        __builtin_amdgcn_global_load_lds(GLB_CAST(gA[c]),
            LDS_CAST(smem + c * 4096 + t * 16), 16, 0, 0);
    #pragma unroll
    for (int c = 0; c < 2; ++c)
        __builtin_amdgcn_global_load_lds(GLB_CAST(gB[c]),
            LDS_CAST(smem + 16384 + c * 4096 + t * 16), 16, 0, 0);
    #pragma unroll
    for (int c = 0; c < 4; ++c)
        __builtin_amdgcn_global_load_lds(GLB_CAST(gA[c] + 32),
            LDS_CAST(smem + 24576 + c * 4096 + t * 16), 16, 0, 0);
    #pragma unroll
    for (int c = 0; c < 2; ++c)
        __builtin_amdgcn_global_load_lds(GLB_CAST(gB[c] + 32),
            LDS_CAST(smem + 24576 + 16384 + c * 4096 + t * 16), 16, 0, 0);
    VMCNT6();
    S_BARRIER();

    for (int tt = 0; tt < NT; ++tt) {
        const __bf16* Asl = (const __bf16*)(smem + (tt & 1) * 24576);
        const __bf16* Bsl = Asl + 8192;
        bf16x8 af[8], bfr[4];
        #pragma unroll
        for (int i = 0; i < 8; ++i) af[i] = *(const bf16x8*)(Asl + offA + i * 512);
        #pragma unroll
        for (int j = 0; j < 4; ++j) bfr[j] = *(const bf16x8*)(Bsl + offB + j * 512);
        __builtin_amdgcn_s_setprio(1);
        #pragma unroll
        for (int i = 0; i < 8; ++i)
            #pragma unroll
            for (int j = 0; j < 4; ++j)
                acc[i][j] = __builtin_amdgcn_mfma_f32_16x16x32_bf16(af[i], bfr[j], acc[i][j], 0, 0, 0);
        __builtin_amdgcn_s_setprio(0);

        if (tt == NT - 1) break;
        S_BARRIER();
        if (tt + 2 < NT) {
            int kk2 = (tt + 2) * 32;
            char* dst = smem + (tt & 1) * 24576;
            #pragma unroll
            for (int c = 0; c < 4; ++c)
                __builtin_amdgcn_global_load_lds(GLB_CAST(gA[c] + kk2),
                    LDS_CAST(dst + c * 4096 + t * 16), 16, 0, 0);
            #pragma unroll
            for (int c = 0; c < 2; ++c)
                __builtin_amdgcn_global_load_lds(GLB_CAST(gB[c] + kk2),
                    LDS_CAST(dst + 16384 + c * 4096 + t * 16), 16, 0, 0);
            VMCNT6();                            // tile t+1 landed; t+2 in flight
        } else {
            VMCNT0();
        }
        S_BARRIER();
    }

    if constexpr (MODE == 0) {
        // transpose epilogue: acc -> swizzled LDS [128 e][256 s] -> coalesced vt
        S_BARRIER();                             // all waves done with staging LDS
        #pragma unroll
        for (int j = 0; j < 4; ++j) {
            int e_loc = wnc * 64 + j * 16 + lr;
            float bias = bv[(nblk << 7) + e_loc];
            #pragma unroll
            for (int i = 0; i < 8; ++i) {
                int slot = wmr * 16 + i * 2 + (lk >> 1);
                bf16x4 o;
                #pragma unroll
                for (int r = 0; r < 4; ++r) o[r] = (__bf16)(acc[i][j][r] + bias);
                *(bf16x4*)(smem + e_loc * 512 + ((slot ^ (e_loc & 7)) << 4) + (lk & 1) * 8) = o;
            }
        }
        S_BARRIER();
        int b = mblk >> 3, sbase = (mblk & 7) << 8;
        #pragma unroll
        for (int u = 0; u < 8; ++u) {
            int e_loc = u * 16 + (t >> 4);
            int e_glob = (nblk << 7) + e_loc;
            __bf16* dst = outVt + (((size_t)(b << 10) + e_glob) << 11) + sbase;
            #pragma unroll
            for (int v = 0; v < 2; ++v) {
                int sv = (t & 15) + (v << 4);
                bf16x8 val = *(const bf16x8*)(smem + e_loc * 512 + ((sv ^ (e_loc & 7)) << 4));
                *(bf16x8*)(dst + sv * 8) = val;
            }
        }
    } else {
        float* ob = outF + (size_t)bb * S * Dd;
        #pragma unroll
        for (int i = 0; i < 8; ++i) {
            int m0 = (mblk << 8) + wmr * 128 + i * 16 + (lk << 2);
            #pragma unroll
            for (int j = 0; j < 4; ++j) {
                int e = (nblk << 7) + wnc * 64 + j * 16 + lr;
                #pragma unroll
                for (int r = 0; r < 4; ++r)
                    ob[(size_t)(m0 + r) * 1024 + e] = acc[i][j][r];
            }
        }
    }
}

// ---------------------------------------------------------------------------
extern "C" void kernel_launch(void* const* d_in, const int* in_sizes, int n_in,
                              void* d_out, int out_size, void* d_ws, size_t ws_size,
                              hipStream_t stream)
{
    const float* x  = (const float*)d_in[0];
    const float* Wq = (const float*)d_in[1];
    const float* bq = (const float*)d_in[2];
    const float* Wk = (const float*)d_in[3];
    const float* bk = (const float*)d_in[4];
    const float* Wv = (const float*)d_in[5];
    const float* bv = (const float*)d_in[6];

    float* outp  = (float*)d_out;
    float* attnF = outp + OUT0;

    if (ws_size < WS_NEED) return;
    char* ws = (char*)d_ws;
    __bf16* xbf   = (__bf16*)(ws + OFF_XBF);
    __bf16* wvt   = (__bf16*)(ws + OFF_WVT);
    float*  qbuf  = (float*)(ws + OFF_Q);
    float*  kbuf  = (float*)(ws + OFF_K);
    __bf16* vt    = (__bf16*)(ws + OFF_VT);
    __bf16* attnB = (__bf16*)(ws + OFF_ATTB);

    prep_kernel<<<4608, 256, 0, stream>>>(x, Wq, Wk, Wv, bq, bk, xbf, wvt, qbuf, kbuf);
    gemm_kernel<0><<<512, 256, 0, stream>>>(xbf, wvt, nullptr, vt, bv);
    softmax_kernel<<<512, 256, 0, stream>>>(qbuf, kbuf, attnF, attnB);
    gemm_kernel<1><<<512, 256, 0, stream>>>(attnB, vt, outp, nullptr, nullptr);
}

// Round 7
// 200.778 us; speedup vs baseline: 1.0409x; 1.0409x over previous
//
#include <hip/hip_runtime.h>

// ---------------------------------------------------------------------------
// FactorizedSynthesizerRandom: B=8, S=2048, D=1024, K=8
//   q = x@Wq+bq, k = x@Wk+bk  (rank-8)
//   attn = softmax(q k^T)                        -> output[1] (f32, 8x2048x2048)
//   out  = attn @ (x@Wv+bv)                      -> output[0] (f32, 8x2048x1024)
// Round 7: dataflow cut. xbf intermediate eliminated: gemm0 is rebuilt as
// C[s][e] with A = x reg-staged from f32 (T14 issue-early, cvt in regs) and
// B = wvt via global_load_lds; coalesced vt writes via LDS-transpose epilogue.
// prep = qk projection + Wv^T only. softmax/gemm1 = round-3 best (8-phase).
// ---------------------------------------------------------------------------

typedef __attribute__((ext_vector_type(8))) __bf16 bf16x8;
typedef __attribute__((ext_vector_type(4))) __bf16 bf16x4;
typedef __attribute__((ext_vector_type(4))) float  f32x4;
typedef unsigned int u32;

#define GLB_CAST(p) ((const __attribute__((address_space(1))) u32*)(p))
#define LDS_CAST(p) ((__attribute__((address_space(3))) u32*)(p))

#define S_BARRIER() { __builtin_amdgcn_s_barrier(); __builtin_amdgcn_sched_barrier(0); }
#define LGKM0()     { asm volatile("s_waitcnt lgkmcnt(0)" ::: "memory"); __builtin_amdgcn_sched_barrier(0); }
#define VMCNT8()    { asm volatile("s_waitcnt vmcnt(8)" ::: "memory"); __builtin_amdgcn_sched_barrier(0); }
#define VMCNT0()    { asm volatile("s_waitcnt vmcnt(0)" ::: "memory"); __builtin_amdgcn_sched_barrier(0); }

static constexpr int    Bn   = 8;
static constexpr int    S    = 2048;
static constexpr int    Dd   = 1024;
static constexpr int    Mtot = Bn * S;            // 16384
static constexpr size_t OUT0 = (size_t)Bn * S * Dd;

// workspace layout (bytes)
static constexpr size_t OFF_WVT  = 0;                                  // [1024][1024] bf16 (Wv^T)
static constexpr size_t OFF_Q    = OFF_WVT + (size_t)Dd * Dd * 2;      // [16384][8] f32
static constexpr size_t OFF_K    = OFF_Q   + (size_t)Mtot * 8 * 4;     // [16384][8] f32
static constexpr size_t OFF_VT   = OFF_K   + (size_t)Mtot * 8 * 4;     // [8][1024][2048] bf16
static constexpr size_t OFF_ATTB = OFF_VT  + (size_t)Bn * Dd * S * 2;  // [8][2048][2048] bf16
static constexpr size_t WS_NEED  = OFF_ATTB + (size_t)Bn * S * S * 2;  // ~99 MB

// ---------------------------------------------------------------------------
// prep: blocks [0,256): q/k projection from f32 x, Wq, Wk (bf16 MFMA);
//       [256,512): Wv -> Wv^T bf16.
// ---------------------------------------------------------------------------
__global__ __launch_bounds__(256) void prep_kernel(
    const float* __restrict__ x, const float* __restrict__ Wq,
    const float* __restrict__ Wk, const float* __restrict__ Wv,
    const float* __restrict__ bq, const float* __restrict__ bk,
    __bf16* __restrict__ wvt, float* __restrict__ qb, float* __restrict__ kb)
{
    __shared__ float lt[64][65];
    int bid = blockIdx.x, t = threadIdx.x;
    if (bid < 256) {
        int l = t & 63, w = t >> 6;
        int mbase = (bid * 4 + w) * 16;
        int n = l & 15;
        int dbase = (l >> 4) << 3;
        const float* xr = x + (size_t)(mbase + n) * 1024 + dbase;
        const float* wcol = (n < 8) ? (Wq + n) : (Wk + (n & 7));
        f32x4 acc = {0.f, 0.f, 0.f, 0.f};
        #pragma unroll 4
        for (int kk = 0; kk < 1024; kk += 32) {
            f32x4 a0 = *(const f32x4*)(xr + kk);
            f32x4 a1 = *(const f32x4*)(xr + kk + 4);
            bf16x8 a, b;
            #pragma unroll
            for (int c = 0; c < 4; ++c) { a[c] = (__bf16)a0[c]; a[4 + c] = (__bf16)a1[c]; }
            #pragma unroll
            for (int u = 0; u < 8; ++u) b[u] = (__bf16)wcol[(size_t)(dbase + kk + u) * 8];
            acc = __builtin_amdgcn_mfma_f32_16x16x32_bf16(a, b, acc, 0, 0, 0);
        }
        float bias = (n < 8) ? bq[n] : bk[n & 7];
        #pragma unroll
        for (int r = 0; r < 4; ++r) {
            int m = mbase + ((l >> 4) << 2) + r;
            float v = acc[r] + bias;
            if (n < 8) qb[m * 8 + n] = v;
            else       kb[m * 8 + (n & 7)] = v;
        }
    } else {
        int tile = bid - 256;
        int tr = tile >> 4, tc = tile & 15;
        int r0 = t >> 6, c = t & 63;
        #pragma unroll
        for (int i = 0; i < 16; ++i) {
            int row = i * 4 + r0;
            lt[row][c] = Wv[(size_t)(tr * 64 + row) * 1024 + tc * 64 + c];
        }
        __syncthreads();
        #pragma unroll
        for (int i = 0; i < 16; ++i) {
            int er = i * 4 + r0;
            wvt[(size_t)(tc * 64 + er) * 1024 + tr * 64 + c] = (__bf16)lt[c][er];
        }
    }
}

// ---------------------------------------------------------------------------
// gemm0: vt[b][e][s] = (x@Wv + bv)^T, computed as C[s][e] = x[s][d] * Wv^T[e][d]^T.
// 512 thr = 8 waves (2M x 4N), wave-tile 128(s) x 64(e), BK=64, NT=16.
// A (x rows, f32): reg-staged — loads for tile t+2 issued BEFORE tile t's
// MFMA (T14), cvt+swizzled ds_write after the post-MFMA barrier. Single
// vmcnt(0)/iter drains only >=1-phase-old ops. B (wvt): global_load_lds,
// pre-swizzled source (slot ^= row&7). Epilogue: acc -> LDS [e 256][s 256]
// bf16 (16B-granule XOR) -> coalesced 128B vt runs + bias.
// ---------------------------------------------------------------------------
__global__ __launch_bounds__(512, 2) void gemm0_kernel(
    const float* __restrict__ X, const __bf16* __restrict__ Wvt,
    __bf16* __restrict__ outVt, const float* __restrict__ bv)
{
    constexpr int NT = 16;
    __shared__ __align__(1024) char smem[131072];

    int bid = blockIdx.x;
    int wg = ((bid & 7) << 5) | (bid >> 3);     // bijective XCD swizzle (nwg=256)
    int t = threadIdx.x, l = t & 63, wid = t >> 6;
    int wmr = wid >> 2, wnc = wid & 3;          // wave grid 2(M=s) x 4(N=e)
    int mblk = wg >> 2, nblk = wg & 3;          // 64 s-panels x 4 e-panels

    // A reg-staging: thread t owns row t>>1 (of 256), half t&1 (32 f32)
    int arow = t >> 1, ahalf = t & 1;
    const float* Ax = X + (size_t)(mblk * 256 + arow) * 1024 + ahalf * 32;
    int awoff[4];
    #pragma unroll
    for (int u = 0; u < 4; ++u)
        awoff[u] = arow * 128 + (((ahalf * 4 + u) ^ (arow & 7)) << 4);  // bytes

    // B staging (wvt, gload_lds): 4 chunks of 64 rows
    int rowin = t >> 3;
    int sl8 = (t & 7) ^ (rowin & 7);
    const __bf16* gB[4];
    #pragma unroll
    for (int c = 0; c < 4; ++c)
        gB[c] = Wvt + (size_t)(nblk * 256 + c * 64 + rowin) * 1024 + sl8 * 8;

    int lr = l & 15, lk = l >> 4;
    // lane-constant fragment offsets (row&7 == lr&7)
    int slot0 = (lk ^ (lr & 7)) << 3;
    int slot1 = ((lk ^ 4) ^ (lr & 7)) << 3;
    int offA0 = (wmr * 128 + lr) * 64 + slot0;
    int offA1 = (wmr * 128 + lr) * 64 + slot1;
    int offB0 = (wnc * 64 + lr) * 64 + slot0;
    int offB1 = (wnc * 64 + lr) * 64 + slot1;

    f32x4 acc[8][4] = {};
    f32x4 xr[8];

    // ---- prologue: stage tiles 0 and 1
    #pragma unroll
    for (int i = 0; i < 8; ++i) xr[i] = *(const f32x4*)(Ax + 0 * 64 + i * 4);
    VMCNT0();
    #pragma unroll
    for (int u = 0; u < 4; ++u) {
        f32x4 a0 = xr[2 * u], a1 = xr[2 * u + 1];
        bf16x8 wv_;
        #pragma unroll
        for (int c = 0; c < 4; ++c) { wv_[c] = (__bf16)a0[c]; wv_[4 + c] = (__bf16)a1[c]; }
        *(bf16x8*)(smem + awoff[u]) = wv_;
    }
    #pragma unroll
    for (int c = 0; c < 4; ++c)
        __builtin_amdgcn_global_load_lds(GLB_CAST(gB[c] + 0),
            LDS_CAST(smem + 32768 + c * 8192 + wid * 1024), 16, 0, 0);
    #pragma unroll
    for (int i = 0; i < 8; ++i) xr[i] = *(const f32x4*)(Ax + 1 * 64 + i * 4);
    VMCNT0();
    #pragma unroll
    for (int u = 0; u < 4; ++u) {
        f32x4 a0 = xr[2 * u], a1 = xr[2 * u + 1];
        bf16x8 wv_;
        #pragma unroll
        for (int c = 0; c < 4; ++c) { wv_[c] = (__bf16)a0[c]; wv_[4 + c] = (__bf16)a1[c]; }
        *(bf16x8*)(smem + 65536 + awoff[u]) = wv_;
    }
    #pragma unroll
    for (int c = 0; c < 4; ++c)
        __builtin_amdgcn_global_load_lds(GLB_CAST(gB[c] + 64),
            LDS_CAST(smem + 65536 + 32768 + c * 8192 + wid * 1024), 16, 0, 0);
    VMCNT0();
    LGKM0();
    S_BARRIER();

    for (int tt = 0; tt < NT; ++tt) {
        bool pf = (tt + 2 < NT);
        // a) issue A-loads for tile tt+2 (fly under the MFMA phase)
        if (pf) {
            #pragma unroll
            for (int i = 0; i < 8; ++i)
                xr[i] = *(const f32x4*)(Ax + (tt + 2) * 64 + i * 4);
            __builtin_amdgcn_sched_barrier(0);
        }
        // b) compute slot tt&1
        const __bf16* Asl = (const __bf16*)(smem + ((tt & 1) << 16));
        const __bf16* Bsl = Asl + 16384;
        bf16x8 af[8], bfr[4];
        #pragma unroll
        for (int i = 0; i < 8; ++i) af[i] = *(const bf16x8*)(Asl + offA0 + i * 1024);
        #pragma unroll
        for (int j = 0; j < 4; ++j) bfr[j] = *(const bf16x8*)(Bsl + offB0 + j * 1024);
        __builtin_amdgcn_s_setprio(1);
        #pragma unroll
        for (int i = 0; i < 8; ++i)
            #pragma unroll
            for (int j = 0; j < 4; ++j)
                acc[i][j] = __builtin_amdgcn_mfma_f32_16x16x32_bf16(af[i], bfr[j], acc[i][j], 0, 0, 0);
        __builtin_amdgcn_s_setprio(0);
        #pragma unroll
        for (int i = 0; i < 8; ++i) af[i] = *(const bf16x8*)(Asl + offA1 + i * 1024);
        #pragma unroll
        for (int j = 0; j < 4; ++j) bfr[j] = *(const bf16x8*)(Bsl + offB1 + j * 1024);
        __builtin_amdgcn_s_setprio(1);
        #pragma unroll
        for (int i = 0; i < 8; ++i)
            #pragma unroll
            for (int j = 0; j < 4; ++j)
                acc[i][j] = __builtin_amdgcn_mfma_f32_16x16x32_bf16(af[i], bfr[j], acc[i][j], 0, 0, 0);
        __builtin_amdgcn_s_setprio(0);

        if (tt == NT - 1) break;
        // c) slot tt&1 fully consumed by all waves
        S_BARRIER();
        // d) drain: A-regs (issued this iter, hid under MFMA) + B gloads
        //    (issued last iter) — never a cold wait.
        VMCNT0();
        // e) stage tile tt+2 into slot tt&1
        if (pf) {
            char* dst = smem + ((tt & 1) << 16);
            #pragma unroll
            for (int u = 0; u < 4; ++u) {
                f32x4 a0 = xr[2 * u], a1 = xr[2 * u + 1];
                bf16x8 wv_;
                #pragma unroll
                for (int c = 0; c < 4; ++c) { wv_[c] = (__bf16)a0[c]; wv_[4 + c] = (__bf16)a1[c]; }
                *(bf16x8*)(dst + awoff[u]) = wv_;
            }
            #pragma unroll
            for (int c = 0; c < 4; ++c)
                __builtin_amdgcn_global_load_lds(GLB_CAST(gB[c] + (tt + 2) * 64),
                    LDS_CAST(dst + 32768 + c * 8192 + wid * 1024), 16, 0, 0);
            LGKM0();
        }
        S_BARRIER();
    }

    // ---- epilogue: acc -> LDS [e 256][s 256] bf16 (granule XOR) -> vt
    S_BARRIER();
    #pragma unroll
    for (int j = 0; j < 4; ++j) {
        int e_loc = wnc * 64 + j * 16 + lr;
        float bias = bv[(nblk << 8) + e_loc];
        #pragma unroll
        for (int i = 0; i < 8; ++i) {
            int slot = wmr * 16 + i * 2 + (lk >> 1);
            bf16x4 o;
            #pragma unroll
            for (int r = 0; r < 4; ++r) o[r] = (__bf16)(acc[i][j][r] + bias);
            *(bf16x4*)(smem + e_loc * 512 + ((slot ^ (e_loc & 7)) << 4) + (lk & 1) * 8) = o;
        }
    }
    S_BARRIER();
    int b = mblk >> 3, sbase = (mblk & 7) << 8;
    #pragma unroll
    for (int u = 0; u < 4; ++u) {
        int e_loc = u * 64 + (t >> 3);
        int e_glob = (nblk << 8) + e_loc;
        __bf16* dstp = outVt + (((size_t)(b << 10) + e_glob) << 11) + sbase;
        int sv = t & 7;
        #pragma unroll
        for (int v = 0; v < 4; ++v) {
            int svv = v * 8 + sv;
            bf16x8 val = *(const bf16x8*)(smem + e_loc * 512 + ((svv ^ (e_loc & 7)) << 4));
            *(bf16x8*)(dstp + svv * 8) = val;
        }
    }
}

// ---------------------------------------------------------------------------
// softmax: thread t owns cols j = t*8..t*8+7, k-slice in registers.
// Writes attn f32 (d_out) and attn bf16 (ws, PV GEMM input).
// ---------------------------------------------------------------------------
__global__ __launch_bounds__(256) void softmax_kernel(
    const float* __restrict__ qb, const float* __restrict__ kb,
    float* __restrict__ attnF, __bf16* __restrict__ attnB)
{
    int bid = blockIdx.x;
    int b = bid >> 6, chunk = bid & 63;
    int t = threadIdx.x, l = t & 63, w = t >> 6;
    float kr[8][8];
    const float* kbb = kb + ((size_t)b << 14);
    #pragma unroll
    for (int jj = 0; jj < 8; ++jj) {
        f32x4 v0 = *(const f32x4*)(kbb + (size_t)(t * 8 + jj) * 8);
        f32x4 v1 = *(const f32x4*)(kbb + (size_t)(t * 8 + jj) * 8 + 4);
        #pragma unroll
        for (int c = 0; c < 4; ++c) { kr[jj][c] = v0[c]; kr[jj][4 + c] = v1[c]; }
    }
    __shared__ float redm[4], reds[4];
    const float* qrow = qb + ((size_t)b << 14);
    for (int ii = 0; ii < 32; ++ii) {
        int i = (chunk << 5) + ii;
        f32x4 q0 = *(const f32x4*)(qrow + (size_t)i * 8);
        f32x4 q1 = *(const f32x4*)(qrow + (size_t)i * 8 + 4);
        float e[8];
        #pragma unroll
        for (int jj = 0; jj < 8; ++jj) {
            float s = q0[0] * kr[jj][0];
            s = fmaf(q0[1], kr[jj][1], s);
            s = fmaf(q0[2], kr[jj][2], s);
            s = fmaf(q0[3], kr[jj][3], s);
            s = fmaf(q1[0], kr[jj][4], s);
            s = fmaf(q1[1], kr[jj][5], s);
            s = fmaf(q1[2], kr[jj][6], s);
            s = fmaf(q1[3], kr[jj][7], s);
            e[jj] = s;
        }
        float mx = e[0];
        #pragma unroll
        for (int jj = 1; jj < 8; ++jj) mx = fmaxf(mx, e[jj]);
        #pragma unroll
        for (int d = 1; d < 64; d <<= 1) mx = fmaxf(mx, __shfl_xor(mx, d));
        if (l == 0) redm[w] = mx;
        __syncthreads();
        mx = fmaxf(fmaxf(redm[0], redm[1]), fmaxf(redm[2], redm[3]));
        float p[8], sum = 0.f;
        #pragma unroll
        for (int jj = 0; jj < 8; ++jj) { p[jj] = __expf(e[jj] - mx); sum += p[jj]; }
        #pragma unroll
        for (int d = 1; d < 64; d <<= 1) sum += __shfl_xor(sum, d);
        if (l == 0) reds[w] = sum;
        __syncthreads();
        float T = (reds[0] + reds[1]) + (reds[2] + reds[3]);
        float inv = 1.0f / T;
        size_t off = (((size_t)b << 11) + i) * 2048 + (size_t)t * 8;
        f32x4 o0, o1; bf16x8 ob;
        #pragma unroll
        for (int c = 0; c < 4; ++c) {
            o0[c] = p[c] * inv; o1[c] = p[4 + c] * inv;
            ob[c] = (__bf16)o0[c]; ob[4 + c] = (__bf16)o1[c];
        }
        *(f32x4*)(attnF + off) = o0;
        *(f32x4*)(attnF + off + 4) = o1;
        *(bf16x8*)(attnB + off) = ob;
    }
}

// ---------------------------------------------------------------------------
// gemm1 (round-3 8-phase, MODE 1): out = attn @ value, f32 [b][i][e].
// A = attnB [b][2048][2048] bf16, Bt = vt [b][1024][2048] bf16, K = 2048.
// ---------------------------------------------------------------------------
__device__ __forceinline__ void g1_stageA(const __bf16* Ab, char* smem,
    int slot, int kk, int c, int rowin, int sl8, int wid)
{
    __builtin_amdgcn_global_load_lds(
        GLB_CAST(Ab + (size_t)(c * 64 + rowin) * 2048 + kk + sl8 * 8),
        LDS_CAST(smem + slot * 65536 + c * 8192 + wid * 1024), 16, 0, 0);
}
__device__ __forceinline__ void g1_stageB(const __bf16* Bb, char* smem,
    int slot, int kk, int c, int rowin, int sl8, int wid)
{
    __builtin_amdgcn_global_load_lds(
        GLB_CAST(Bb + (size_t)(c * 64 + rowin) * 2048 + kk + sl8 * 8),
        LDS_CAST(smem + slot * 65536 + 32768 + c * 8192 + wid * 1024), 16, 0, 0);
}

__global__ __launch_bounds__(512, 2) void gemm1_kernel(
    const __bf16* __restrict__ A, const __bf16* __restrict__ Bt,
    float* __restrict__ outF)
{
    constexpr int NT = 32;
    __shared__ __align__(1024) char smem[131072];

    int bid = blockIdx.x;
    int wg = ((bid & 7) << 5) | (bid >> 3);     // bijective XCD swizzle (nwg=256)
    int t = threadIdx.x, l = t & 63;
    int wid = t >> 6;
    int wmr = wid >> 2, wnc = wid & 3;

    int bb = wg >> 5; int r = wg & 31;          // one batch per XCD
    int mblk = r >> 2, nblk = r & 3;
    const __bf16* Ab = A + (size_t)bb * S * S + (size_t)mblk * 256 * 2048;
    const __bf16* Bb = Bt + (size_t)bb * Dd * S + (size_t)nblk * 256 * 2048;

    int rowin = t >> 3;
    int sl8 = (t & 7) ^ (rowin & 7);
    int lr = l & 15, lk = l >> 4;

    f32x4 acc[8][4] = {};

    #pragma unroll
    for (int c = 0; c < 4; ++c) {
        g1_stageA(Ab, smem, 0, 0, c, rowin, sl8, wid);
        g1_stageB(Bb, smem, 0, 0, c, rowin, sl8, wid);
    }
    #pragma unroll
    for (int c = 0; c < 4; ++c) {
        g1_stageA(Ab, smem, 1, 64, c, rowin, sl8, wid);
        g1_stageB(Bb, smem, 1, 64, c, rowin, sl8, wid);
    }
    VMCNT8();
    S_BARRIER();

    for (int tt = 0; tt < NT; ++tt) {
        int s = tt & 1;
        const __bf16* Asl = (const __bf16*)(smem + s * 65536);
        const __bf16* Bsl = (const __bf16*)(smem + s * 65536 + 32768);
        bool pf = (tt + 2 < NT);
        int kk2 = (tt + 2) * 64;

        bf16x8 aLo[2][4], aHi[2][4], bLo[2][2], bHi[2][2];

        // ---- P0: read A-lo + B-lo; MFMA Q00
        #pragma unroll
        for (int ks = 0; ks < 2; ++ks) {
            int sa = ks * 4 + lk;
            #pragma unroll
            for (int i = 0; i < 4; ++i) {
                int ra = wmr * 128 + i * 16 + lr;
                aLo[ks][i] = *(const bf16x8*)&Asl[ra * 64 + ((sa ^ (ra & 7)) << 3)];
            }
            #pragma unroll
            for (int j = 0; j < 2; ++j) {
                int rb = wnc * 64 + j * 16 + lr;
                bLo[ks][j] = *(const bf16x8*)&Bsl[rb * 64 + ((sa ^ (rb & 7)) << 3)];
            }
        }
        S_BARRIER(); LGKM0();
        __builtin_amdgcn_s_setprio(1);
        #pragma unroll
        for (int ks = 0; ks < 2; ++ks)
            #pragma unroll
            for (int i = 0; i < 4; ++i)
                #pragma unroll
                for (int j = 0; j < 2; ++j)
                    acc[i][j] = __builtin_amdgcn_mfma_f32_16x16x32_bf16(aLo[ks][i], bLo[ks][j], acc[i][j], 0, 0, 0);
        __builtin_amdgcn_s_setprio(0);
        S_BARRIER();

        // ---- P1: read B-hi; stage A0,A2(t+2); MFMA Q01
        #pragma unroll
        for (int ks = 0; ks < 2; ++ks) {
            int sa = ks * 4 + lk;
            #pragma unroll
            for (int j = 0; j < 2; ++j) {
                int rb = wnc * 64 + (j + 2) * 16 + lr;
                bHi[ks][j] = *(const bf16x8*)&Bsl[rb * 64 + ((sa ^ (rb & 7)) << 3)];
            }
        }
        if (pf) {
            g1_stageA(Ab, smem, s, kk2, 0, rowin, sl8, wid);
            g1_stageA(Ab, smem, s, kk2, 2, rowin, sl8, wid);
        }
        S_BARRIER(); LGKM0();
        __builtin_amdgcn_s_setprio(1);
        #pragma unroll
        for (int ks = 0; ks < 2; ++ks)
            #pragma unroll
            for (int i = 0; i < 4; ++i)
                #pragma unroll
                for (int j = 0; j < 2; ++j)
                    acc[i][2 + j] = __builtin_amdgcn_mfma_f32_16x16x32_bf16(aLo[ks][i], bHi[ks][j], acc[i][2 + j], 0, 0, 0);
        __builtin_amdgcn_s_setprio(0);
        S_BARRIER();

        // ---- P2: read A-hi; stage B0-3(t+2); MFMA Q11
        #pragma unroll
        for (int ks = 0; ks < 2; ++ks) {
            int sa = ks * 4 + lk;
            #pragma unroll
            for (int i = 0; i < 4; ++i) {
                int ra = wmr * 128 + (i + 4) * 16 + lr;
                aHi[ks][i] = *(const bf16x8*)&Asl[ra * 64 + ((sa ^ (ra & 7)) << 3)];
            }
        }
        if (pf) {
            #pragma unroll
            for (int c = 0; c < 4; ++c)
                g1_stageB(Bb, smem, s, kk2, c, rowin, sl8, wid);
        }
        S_BARRIER(); LGKM0();
        __builtin_amdgcn_s_setprio(1);
        #pragma unroll
        for (int ks = 0; ks < 2; ++ks)
            #pragma unroll
            for (int i = 0; i < 4; ++i)
                #pragma unroll
                for (int j = 0; j < 2; ++j)
                    acc[4 + i][2 + j] = __builtin_amdgcn_mfma_f32_16x16x32_bf16(aHi[ks][i], bHi[ks][j], acc[4 + i][2 + j], 0, 0, 0);
        __builtin_amdgcn_s_setprio(0);
        S_BARRIER();

        // ---- P3: stage A1,A3(t+2); MFMA Q10
        if (pf) {
            g1_stageA(Ab, smem, s, kk2, 1, rowin, sl8, wid);
            g1_stageA(Ab, smem, s, kk2, 3, rowin, sl8, wid);
        }
        S_BARRIER();
        __builtin_amdgcn_s_setprio(1);
        #pragma unroll
        for (int ks = 0; ks < 2; ++ks)
            #pragma unroll
            for (int i = 0; i < 4; ++i)
                #pragma unroll
                for (int j = 0; j < 2; ++j)
                    acc[4 + i][j] = __builtin_amdgcn_mfma_f32_16x16x32_bf16(aHi[ks][i], bLo[ks][j], acc[4 + i][j], 0, 0, 0);
        __builtin_amdgcn_s_setprio(0);

        if (tt == NT - 1) break;
        S_BARRIER();
        if (pf) { VMCNT8(); } else { VMCNT0(); }
        S_BARRIER();
    }

    float* ob = outF + (size_t)bb * S * Dd;
    #pragma unroll
    for (int i = 0; i < 8; ++i) {
        int m0 = (mblk << 8) + wmr * 128 + i * 16 + (lk << 2);
        #pragma unroll
        for (int j = 0; j < 4; ++j) {
            int e = (nblk << 8) + wnc * 64 + j * 16 + lr;
            #pragma unroll
            for (int r = 0; r < 4; ++r)
                ob[(size_t)(m0 + r) * 1024 + e] = acc[i][j][r];
        }
    }
}

// ---------------------------------------------------------------------------
extern "C" void kernel_launch(void* const* d_in, const int* in_sizes, int n_in,
                              void* d_out, int out_size, void* d_ws, size_t ws_size,
                              hipStream_t stream)
{
    const float* x  = (const float*)d_in[0];
    const float* Wq = (const float*)d_in[1];
    const float* bq = (const float*)d_in[2];
    const float* Wk = (const float*)d_in[3];
    const float* bk = (const float*)d_in[4];
    const float* Wv = (const float*)d_in[5];
    const float* bv = (const float*)d_in[6];

    float* outp  = (float*)d_out;
    float* attnF = outp + OUT0;

    if (ws_size < WS_NEED) return;
    char* ws = (char*)d_ws;
    __bf16* wvt   = (__bf16*)(ws + OFF_WVT);
    float*  qbuf  = (float*)(ws + OFF_Q);
    float*  kbuf  = (float*)(ws + OFF_K);
    __bf16* vt    = (__bf16*)(ws + OFF_VT);
    __bf16* attnB = (__bf16*)(ws + OFF_ATTB);

    prep_kernel<<<512, 256, 0, stream>>>(x, Wq, Wk, Wv, bq, bk, wvt, qbuf, kbuf);
    gemm0_kernel<<<256, 512, 0, stream>>>(x, wvt, vt, bv);
    softmax_kernel<<<512, 256, 0, stream>>>(qbuf, kbuf, attnF, attnB);
    gemm1_kernel<<<256, 512, 0, stream>>>(attnB, vt, outp);
}

// Round 8
// 187.099 us; speedup vs baseline: 1.1170x; 1.0731x over previous
//
#include <hip/hip_runtime.h>

// ---------------------------------------------------------------------------
// FactorizedSynthesizerRandom: B=8, S=2048, D=1024, K=8
//   q = x@Wq+bq, k = x@Wk+bk  (rank-8)
//   attn = softmax(q k^T)                        -> output[1] (f32, 8x2048x2048)
//   out  = attn @ (x@Wv+bv)                      -> output[0] (f32, 8x2048x1024)
// Round 8: restore round-3 (best, 196us) + fuse gemm0 and softmax into ONE
// launch as role-split blocks. gemm0 becomes m97-class 128x128/BK64/4-wave/
// single-buffer (32KB LDS, ~3 blocks/CU) so gemm-blocks and softmax-blocks
// co-reside per CU: softmax's HBM writes overlap gemm0's barrier stalls.
// gemm1 = round-3 8-phase verbatim.
// ---------------------------------------------------------------------------

typedef __attribute__((ext_vector_type(8))) __bf16 bf16x8;
typedef __attribute__((ext_vector_type(4))) __bf16 bf16x4;
typedef __attribute__((ext_vector_type(4))) float  f32x4;
typedef unsigned int u32;

#define GLB_CAST(p) ((const __attribute__((address_space(1))) u32*)(p))
#define LDS_CAST(p) ((__attribute__((address_space(3))) u32*)(p))

#define S_BARRIER() { __builtin_amdgcn_s_barrier(); __builtin_amdgcn_sched_barrier(0); }
#define LGKM0()     { asm volatile("s_waitcnt lgkmcnt(0)" ::: "memory"); __builtin_amdgcn_sched_barrier(0); }
#define VMCNT8()    { asm volatile("s_waitcnt vmcnt(8)" ::: "memory"); __builtin_amdgcn_sched_barrier(0); }
#define VMCNT0()    { asm volatile("s_waitcnt vmcnt(0)" ::: "memory"); __builtin_amdgcn_sched_barrier(0); }

static constexpr int    Bn   = 8;
static constexpr int    S    = 2048;
static constexpr int    Dd   = 1024;
static constexpr int    Mtot = Bn * S;            // 16384
static constexpr size_t OUT0 = (size_t)Bn * S * Dd;

// workspace layout (bytes) — round-3 layout
static constexpr size_t OFF_XBF  = 0;                                  // [16384][1024] bf16
static constexpr size_t OFF_WVT  = OFF_XBF + (size_t)Mtot * Dd * 2;    // [1024][1024] bf16 (Wv^T)
static constexpr size_t OFF_WQKT = OFF_WVT + (size_t)Dd * Dd * 2;      // [16][1024] bf16
static constexpr size_t OFF_Q    = OFF_WQKT + (size_t)16 * Dd * 2;     // [16384][8] f32
static constexpr size_t OFF_K    = OFF_Q   + (size_t)Mtot * 8 * 4;     // [16384][8] f32
static constexpr size_t OFF_VT   = OFF_K   + (size_t)Mtot * 8 * 4;     // [8][1024][2048] bf16
static constexpr size_t OFF_ATTB = OFF_VT  + (size_t)Bn * Dd * S * 2;  // [8][2048][2048] bf16
static constexpr size_t WS_NEED  = OFF_ATTB + (size_t)Bn * S * S * 2;  // ~137 MB

// ---------------------------------------------------------------------------
// prep (round-3): [0,4096): x f32->bf16 ; [4096,4352): Wv->Wv^T bf16 ;
//                 [4352,4368): [Wq|Wk]^T bf16
// ---------------------------------------------------------------------------
__global__ __launch_bounds__(256) void prep_kernel(
    const float* __restrict__ x, const float* __restrict__ Wq,
    const float* __restrict__ Wk, const float* __restrict__ Wv,
    __bf16* __restrict__ xbf, __bf16* __restrict__ wvt, __bf16* __restrict__ wqkT)
{
    __shared__ float lt[64][65];
    int bid = blockIdx.x, t = threadIdx.x;
    if (bid < 4096) {
        #pragma unroll
        for (int i = 0; i < 4; ++i) {
            size_t idx4 = (size_t)i * 1048576 + (size_t)bid * 256 + t;
            f32x4 v = ((const f32x4*)x)[idx4];
            bf16x4 o;
            #pragma unroll
            for (int c = 0; c < 4; ++c) o[c] = (__bf16)v[c];
            ((bf16x4*)xbf)[idx4] = o;
        }
    } else if (bid < 4352) {
        int tile = bid - 4096;
        int tr = tile >> 4, tc = tile & 15;
        int r0 = t >> 6, c = t & 63;
        #pragma unroll
        for (int i = 0; i < 16; ++i) {
            int row = i * 4 + r0;
            lt[row][c] = Wv[(size_t)(tr * 64 + row) * 1024 + tc * 64 + c];
        }
        __syncthreads();
        #pragma unroll
        for (int i = 0; i < 16; ++i) {
            int er = i * 4 + r0;
            wvt[(size_t)(tc * 64 + er) * 1024 + tr * 64 + c] = (__bf16)lt[c][er];
        }
    } else {
        int lb = bid - 4352;
        #pragma unroll
        for (int i = 0; i < 4; ++i) {
            int idx = (lb * 4 + i) * 256 + t;
            int n = idx >> 10, d = idx & 1023;
            float v = (n < 8) ? Wq[d * 8 + n] : Wk[d * 8 + (n & 7)];
            wqkT[n * 1024 + d] = (__bf16)v;
        }
    }
}

// ---------------------------------------------------------------------------
// q/k projection (round-3)
// ---------------------------------------------------------------------------
__global__ __launch_bounds__(256) void qk_proj_kernel(
    const __bf16* __restrict__ xbf, const __bf16* __restrict__ wqkT,
    const float* __restrict__ bq, const float* __restrict__ bk,
    float* __restrict__ qb, float* __restrict__ kb)
{
    int t = threadIdx.x, l = t & 63, w = t >> 6;
    int mbase = (blockIdx.x * 4 + w) * 16;
    f32x4 acc = {0.f, 0.f, 0.f, 0.f};
    const __bf16* ar = xbf + (size_t)(mbase + (l & 15)) * 1024 + ((l >> 4) << 3);
    const __bf16* br = wqkT + (size_t)(l & 15) * 1024 + ((l >> 4) << 3);
    #pragma unroll 8
    for (int kk = 0; kk < 1024; kk += 32) {
        bf16x8 a = *(const bf16x8*)(ar + kk);
        bf16x8 b = *(const bf16x8*)(br + kk);
        acc = __builtin_amdgcn_mfma_f32_16x16x32_bf16(a, b, acc, 0, 0, 0);
    }
    int n = l & 15;
    float bias = (n < 8) ? bq[n] : bk[n & 7];
    #pragma unroll
    for (int r = 0; r < 4; ++r) {
        int m = mbase + ((l >> 4) << 2) + r;
        float v = acc[r] + bias;
        if (n < 8) qb[m * 8 + n] = v;
        else       kb[m * 8 + (n & 7)] = v;
    }
}

// ---------------------------------------------------------------------------
// fused gemm0 || softmax. Grid 1536 x 256 threads.
// Segments of 256 blocks: 0=G,1=S,2=G,3=S,4=G,5=G  (1024 gemm tiles, 512 sm
// chunks) so the round-robin dispatcher mixes roles on every CU.
// gemm0 path: m97-class vt-tile: C[128(s) x 128(e)] = xbf * wvt^T, BK=64,
//   4 waves (2x2, wave 64x64), single-buffered 32KB LDS, XOR swizzle
//   slot^=row&7 via pre-swizzled global source, 2 syncthreads per K-tile.
//   Writes vt[b][e][s] bf16 + bias (scattered bf16x4, as round-3).
// softmax path: round-3 softmax verbatim (one 32-row chunk per block).
// ---------------------------------------------------------------------------
__global__ __launch_bounds__(256) void fused_gs_kernel(
    const __bf16* __restrict__ xbf, const __bf16* __restrict__ wvt,
    const float* __restrict__ bv,
    const float* __restrict__ qb, const float* __restrict__ kb,
    __bf16* __restrict__ vtOut, float* __restrict__ attnF,
    __bf16* __restrict__ attnB)
{
    __shared__ __align__(1024) char smem[32768];
    __shared__ float redm[4], reds[4];
    int bid = blockIdx.x, t = threadIdx.x;
    int seg = bid >> 8;
    int gid = -1, sid = -1;
    if (seg == 0) gid = bid;
    else if (seg == 1) sid = bid - 256;
    else if (seg == 2) gid = bid - 256;
    else if (seg == 3) sid = bid - 512;
    else gid = bid - 512;                        // segs 4,5 -> gid 512..1023

    if (sid < 0) {
        // ================= gemm0 (m97-class) =================
        int g = ((gid & 7) << 7) | (gid >> 3);   // bijective XCD swizzle (1024)
        int mblk = g >> 3, nblk = g & 7;         // 128 x 8
        int l = t & 63, wid = t >> 6;
        int wmr = wid >> 1, wnc = wid & 1;       // 2(M) x 2(N) waves
        int lr = l & 15, lk = l >> 4;

        // staging: instr c in {0..3} covers rows c*32 + (t>>3); pre-swizzled src
        int srow = t >> 3;                       // 0..31
        int ssl  = (t & 7) ^ (srow & 7);
        const __bf16* gA = xbf + (size_t)(mblk * 128 + srow) * 1024 + ssl * 8;
        const __bf16* gB = wvt + (size_t)(nblk * 128 + srow) * 1024 + ssl * 8;

        // lane-constant fragment offsets (row&7 == lr&7)
        int s0 = (lk ^ (lr & 7)) << 3;
        int s1 = ((lk ^ 4) ^ (lr & 7)) << 3;
        int offA0 = (wmr * 64 + lr) * 64 + s0;
        int offA1 = (wmr * 64 + lr) * 64 + s1;
        int offB0 = (wnc * 64 + lr) * 64 + s0;
        int offB1 = (wnc * 64 + lr) * 64 + s1;

        f32x4 acc[4][4] = {};

        for (int tt = 0; tt < 16; ++tt) {
            int kk = tt * 64;
            #pragma unroll
            for (int c = 0; c < 4; ++c) {
                __builtin_amdgcn_global_load_lds(
                    GLB_CAST(gA + (size_t)c * 32 * 1024 + kk),
                    LDS_CAST(smem + c * 4096 + wid * 1024), 16, 0, 0);
                __builtin_amdgcn_global_load_lds(
                    GLB_CAST(gB + (size_t)c * 32 * 1024 + kk),
                    LDS_CAST(smem + 16384 + c * 4096 + wid * 1024), 16, 0, 0);
            }
            __syncthreads();                      // drains vmcnt; LDS valid
            const __bf16* As = (const __bf16*)smem;
            const __bf16* Bs = (const __bf16*)(smem + 16384);
            bf16x8 af[4], bfr[4];
            #pragma unroll
            for (int i = 0; i < 4; ++i) af[i]  = *(const bf16x8*)(As + offA0 + i * 1024);
            #pragma unroll
            for (int j = 0; j < 4; ++j) bfr[j] = *(const bf16x8*)(Bs + offB0 + j * 1024);
            #pragma unroll
            for (int i = 0; i < 4; ++i)
                #pragma unroll
                for (int j = 0; j < 4; ++j)
                    acc[i][j] = __builtin_amdgcn_mfma_f32_16x16x32_bf16(af[i], bfr[j], acc[i][j], 0, 0, 0);
            #pragma unroll
            for (int i = 0; i < 4; ++i) af[i]  = *(const bf16x8*)(As + offA1 + i * 1024);
            #pragma unroll
            for (int j = 0; j < 4; ++j) bfr[j] = *(const bf16x8*)(Bs + offB1 + j * 1024);
            #pragma unroll
            for (int i = 0; i < 4; ++i)
                #pragma unroll
                for (int j = 0; j < 4; ++j)
                    acc[i][j] = __builtin_amdgcn_mfma_f32_16x16x32_bf16(af[i], bfr[j], acc[i][j], 0, 0, 0);
            __syncthreads();                      // all reads done before overwrite
        }

        #pragma unroll
        for (int j = 0; j < 4; ++j) {
            int e = (nblk << 7) + wnc * 64 + j * 16 + lr;
            float bias = bv[e];
            #pragma unroll
            for (int i = 0; i < 4; ++i) {
                int m0 = (mblk << 7) + wmr * 64 + i * 16 + (lk << 2);
                int b = m0 >> 11, sA = m0 & 2047;
                bf16x4 o;
                #pragma unroll
                for (int r = 0; r < 4; ++r) o[r] = (__bf16)(acc[i][j][r] + bias);
                *(bf16x4*)&vtOut[(((size_t)(b << 10) + e) << 11) + sA] = o;
            }
        }
    } else {
        // ================= softmax (round-3 verbatim) =================
        int b = sid >> 6, chunk = sid & 63;
        int l = t & 63, w = t >> 6;
        float kr[8][8];
        const float* kbb = kb + ((size_t)b << 14);
        #pragma unroll
        for (int jj = 0; jj < 8; ++jj) {
            f32x4 v0 = *(const f32x4*)(kbb + (size_t)(t * 8 + jj) * 8);
            f32x4 v1 = *(const f32x4*)(kbb + (size_t)(t * 8 + jj) * 8 + 4);
            #pragma unroll
            for (int c = 0; c < 4; ++c) { kr[jj][c] = v0[c]; kr[jj][4 + c] = v1[c]; }
        }
        const float* qrow = qb + ((size_t)b << 14);
        for (int ii = 0; ii < 32; ++ii) {
            int i = (chunk << 5) + ii;
            f32x4 q0 = *(const f32x4*)(qrow + (size_t)i * 8);
            f32x4 q1 = *(const f32x4*)(qrow + (size_t)i * 8 + 4);
            float e[8];
            #pragma unroll
            for (int jj = 0; jj < 8; ++jj) {
                float s = q0[0] * kr[jj][0];
                s = fmaf(q0[1], kr[jj][1], s);
                s = fmaf(q0[2], kr[jj][2], s);
                s = fmaf(q0[3], kr[jj][3], s);
                s = fmaf(q1[0], kr[jj][4], s);
                s = fmaf(q1[1], kr[jj][5], s);
                s = fmaf(q1[2], kr[jj][6], s);
                s = fmaf(q1[3], kr[jj][7], s);
                e[jj] = s;
            }
            float mx = e[0];
            #pragma unroll
            for (int jj = 1; jj < 8; ++jj) mx = fmaxf(mx, e[jj]);
            #pragma unroll
            for (int d = 1; d < 64; d <<= 1) mx = fmaxf(mx, __shfl_xor(mx, d));
            if (l == 0) redm[w] = mx;
            __syncthreads();
            mx = fmaxf(fmaxf(redm[0], redm[1]), fmaxf(redm[2], redm[3]));
            float p[8], sum = 0.f;
            #pragma unroll
            for (int jj = 0; jj < 8; ++jj) { p[jj] = __expf(e[jj] - mx); sum += p[jj]; }
            #pragma unroll
            for (int d = 1; d < 64; d <<= 1) sum += __shfl_xor(sum, d);
            if (l == 0) reds[w] = sum;
            __syncthreads();
            float T = (reds[0] + reds[1]) + (reds[2] + reds[3]);
            float inv = 1.0f / T;
            size_t off = (((size_t)b << 11) + i) * 2048 + (size_t)t * 8;
            f32x4 o0, o1; bf16x8 ob;
            #pragma unroll
            for (int c = 0; c < 4; ++c) {
                o0[c] = p[c] * inv; o1[c] = p[4 + c] * inv;
                ob[c] = (__bf16)o0[c]; ob[4 + c] = (__bf16)o1[c];
            }
            *(f32x4*)(attnF + off) = o0;
            *(f32x4*)(attnF + off + 4) = o1;
            *(bf16x8*)(attnB + off) = ob;
        }
    }
}

// ---------------------------------------------------------------------------
// gemm1 (round-3 8-phase verbatim): out = attn @ value, f32 [b][i][e].
// A = attnB [b][2048][2048] bf16, Bt = vt [b][1024][2048] bf16, K = 2048.
// ---------------------------------------------------------------------------
__device__ __forceinline__ void g1_stageA(const __bf16* Ab, char* smem,
    int slot, int kk, int c, int rowin, int sl8, int wid)
{
    __builtin_amdgcn_global_load_lds(
        GLB_CAST(Ab + (size_t)(c * 64 + rowin) * 2048 + kk + sl8 * 8),
        LDS_CAST(smem + slot * 65536 + c * 8192 + wid * 1024), 16, 0, 0);
}
__device__ __forceinline__ void g1_stageB(const __bf16* Bb, char* smem,
    int slot, int kk, int c, int rowin, int sl8, int wid)
{
    __builtin_amdgcn_global_load_lds(
        GLB_CAST(Bb + (size_t)(c * 64 + rowin) * 2048 + kk + sl8 * 8),
        LDS_CAST(smem + slot * 65536 + 32768 + c * 8192 + wid * 1024), 16, 0, 0);
}

__global__ __launch_bounds__(512, 2) void gemm1_kernel(
    const __bf16* __restrict__ A, const __bf16* __restrict__ Bt,
    float* __restrict__ outF)
{
    constexpr int NT = 32;
    __shared__ __align__(1024) char smem[131072];

    int bid = blockIdx.x;
    int wg = ((bid & 7) << 5) | (bid >> 3);     // bijective XCD swizzle (nwg=256)
    int t = threadIdx.x, l = t & 63;
    int wid = t >> 6;
    int wmr = wid >> 2, wnc = wid & 3;

    int bb = wg >> 5; int r = wg & 31;          // one batch per XCD
    int mblk = r >> 2, nblk = r & 3;
    const __bf16* Ab = A + (size_t)bb * S * S + (size_t)mblk * 256 * 2048;
    const __bf16* Bb = Bt + (size_t)bb * Dd * S + (size_t)nblk * 256 * 2048;

    int rowin = t >> 3;
    int sl8 = (t & 7) ^ (rowin & 7);
    int lr = l & 15, lk = l >> 4;

    f32x4 acc[8][4] = {};

    #pragma unroll
    for (int c = 0; c < 4; ++c) {
        g1_stageA(Ab, smem, 0, 0, c, rowin, sl8, wid);
        g1_stageB(Bb, smem, 0, 0, c, rowin, sl8, wid);
    }
    #pragma unroll
    for (int c = 0; c < 4; ++c) {
        g1_stageA(Ab, smem, 1, 64, c, rowin, sl8, wid);
        g1_stageB(Bb, smem, 1, 64, c, rowin, sl8, wid);
    }
    VMCNT8();
    S_BARRIER();

    for (int tt = 0; tt < NT; ++tt) {
        int s = tt & 1;
        const __bf16* Asl = (const __bf16*)(smem + s * 65536);
        const __bf16* Bsl = (const __bf16*)(smem + s * 65536 + 32768);
        bool pf = (tt + 2 < NT);
        int kk2 = (tt + 2) * 64;

        bf16x8 aLo[2][4], aHi[2][4], bLo[2][2], bHi[2][2];

        // ---- P0
        #pragma unroll
        for (int ks = 0; ks < 2; ++ks) {
            int sa = ks * 4 + lk;
            #pragma unroll
            for (int i = 0; i < 4; ++i) {
                int ra = wmr * 128 + i * 16 + lr;
                aLo[ks][i] = *(const bf16x8*)&Asl[ra * 64 + ((sa ^ (ra & 7)) << 3)];
            }
            #pragma unroll
            for (int j = 0; j < 2; ++j) {
                int rb = wnc * 64 + j * 16 + lr;
                bLo[ks][j] = *(const bf16x8*)&Bsl[rb * 64 + ((sa ^ (rb & 7)) << 3)];
            }
        }
        S_BARRIER(); LGKM0();
        __builtin_amdgcn_s_setprio(1);
        #pragma unroll
        for (int ks = 0; ks < 2; ++ks)
            #pragma unroll
            for (int i = 0; i < 4; ++i)
                #pragma unroll
                for (int j = 0; j < 2; ++j)
                    acc[i][j] = __builtin_amdgcn_mfma_f32_16x16x32_bf16(aLo[ks][i], bLo[ks][j], acc[i][j], 0, 0, 0);
        __builtin_amdgcn_s_setprio(0);
        S_BARRIER();

        // ---- P1
        #pragma unroll
        for (int ks = 0; ks < 2; ++ks) {
            int sa = ks * 4 + lk;
            #pragma unroll
            for (int j = 0; j < 2; ++j) {
                int rb = wnc * 64 + (j + 2) * 16 + lr;
                bHi[ks][j] = *(const bf16x8*)&Bsl[rb * 64 + ((sa ^ (rb & 7)) << 3)];
            }
        }
        if (pf) {
            g1_stageA(Ab, smem, s, kk2, 0, rowin, sl8, wid);
            g1_stageA(Ab, smem, s, kk2, 2, rowin, sl8, wid);
        }
        S_BARRIER(); LGKM0();
        __builtin_amdgcn_s_setprio(1);
        #pragma unroll
        for (int ks = 0; ks < 2; ++ks)
            #pragma unroll
            for (int i = 0; i < 4; ++i)
                #pragma unroll
                for (int j = 0; j < 2; ++j)
                    acc[i][2 + j] = __builtin_amdgcn_mfma_f32_16x16x32_bf16(aLo[ks][i], bHi[ks][j], acc[i][2 + j], 0, 0, 0);
        __builtin_amdgcn_s_setprio(0);
        S_BARRIER();

        // ---- P2
        #pragma unroll
        for (int ks = 0; ks < 2; ++ks) {
            int sa = ks * 4 + lk;
            #pragma unroll
            for (int i = 0; i < 4; ++i) {
                int ra = wmr * 128 + (i + 4) * 16 + lr;
                aHi[ks][i] = *(const bf16x8*)&Asl[ra * 64 + ((sa ^ (ra & 7)) << 3)];
            }
        }
        if (pf) {
            #pragma unroll
            for (int c = 0; c < 4; ++c)
                g1_stageB(Bb, smem, s, kk2, c, rowin, sl8, wid);
        }
        S_BARRIER(); LGKM0();
        __builtin_amdgcn_s_setprio(1);
        #pragma unroll
        for (int ks = 0; ks < 2; ++ks)
            #pragma unroll
            for (int i = 0; i < 4; ++i)
                #pragma unroll
                for (int j = 0; j < 2; ++j)
                    acc[4 + i][2 + j] = __builtin_amdgcn_mfma_f32_16x16x32_bf16(aHi[ks][i], bHi[ks][j], acc[4 + i][2 + j], 0, 0, 0);
        __builtin_amdgcn_s_setprio(0);
        S_BARRIER();

        // ---- P3
        if (pf) {
            g1_stageA(Ab, smem, s, kk2, 1, rowin, sl8, wid);
            g1_stageA(Ab, smem, s, kk2, 3, rowin, sl8, wid);
        }
        S_BARRIER();
        __builtin_amdgcn_s_setprio(1);
        #pragma unroll
        for (int ks = 0; ks < 2; ++ks)
            #pragma unroll
            for (int i = 0; i < 4; ++i)
                #pragma unroll
                for (int j = 0; j < 2; ++j)
                    acc[4 + i][j] = __builtin_amdgcn_mfma_f32_16x16x32_bf16(aHi[ks][i], bLo[ks][j], acc[4 + i][j], 0, 0, 0);
        __builtin_amdgcn_s_setprio(0);

        if (tt == NT - 1) break;
        S_BARRIER();
        if (pf) { VMCNT8(); } else { VMCNT0(); }
        S_BARRIER();
    }

    float* ob = outF + (size_t)bb * S * Dd;
    #pragma unroll
    for (int i = 0; i < 8; ++i) {
        int m0 = (mblk << 8) + wmr * 128 + i * 16 + (lk << 2);
        #pragma unroll
        for (int j = 0; j < 4; ++j) {
            int e = (nblk << 8) + wnc * 64 + j * 16 + lr;
            #pragma unroll
            for (int r = 0; r < 4; ++r)
                ob[(size_t)(m0 + r) * 1024 + e] = acc[i][j][r];
        }
    }
}

// ---------------------------------------------------------------------------
extern "C" void kernel_launch(void* const* d_in, const int* in_sizes, int n_in,
                              void* d_out, int out_size, void* d_ws, size_t ws_size,
                              hipStream_t stream)
{
    const float* x  = (const float*)d_in[0];
    const float* Wq = (const float*)d_in[1];
    const float* bq = (const float*)d_in[2];
    const float* Wk = (const float*)d_in[3];
    const float* bk = (const float*)d_in[4];
    const float* Wv = (const float*)d_in[5];
    const float* bv = (const float*)d_in[6];

    float* outp  = (float*)d_out;
    float* attnF = outp + OUT0;

    if (ws_size < WS_NEED) return;
    char* ws = (char*)d_ws;
    __bf16* xbf   = (__bf16*)(ws + OFF_XBF);
    __bf16* wvt   = (__bf16*)(ws + OFF_WVT);
    __bf16* wqkT  = (__bf16*)(ws + OFF_WQKT);
    float*  qbuf  = (float*)(ws + OFF_Q);
    float*  kbuf  = (float*)(ws + OFF_K);
    __bf16* vt    = (__bf16*)(ws + OFF_VT);
    __bf16* attnB = (__bf16*)(ws + OFF_ATTB);

    prep_kernel<<<4368, 256, 0, stream>>>(x, Wq, Wk, Wv, xbf, wvt, wqkT);
    qk_proj_kernel<<<256, 256, 0, stream>>>(xbf, wqkT, bq, bk, qbuf, kbuf);
    fused_gs_kernel<<<1536, 256, 0, stream>>>(xbf, wvt, bv, qbuf, kbuf, vt, attnF, attnB);
    gemm1_kernel<<<256, 512, 0, stream>>>(attnB, vt, outp);
}

// Round 9
// 185.684 us; speedup vs baseline: 1.1255x; 1.0076x over previous
//
#include <hip/hip_runtime.h>

// ---------------------------------------------------------------------------
// FactorizedSynthesizerRandom: B=8, S=2048, D=1024, K=8
//   q = x@Wq+bq, k = x@Wk+bk  (rank-8)
//   attn = softmax(q k^T)                        -> output[1] (f32, 8x2048x2048)
//   out  = attn @ (x@Wv+bv)                      -> output[0] (f32, 8x2048x1024)
// Round 9: round-8 (187us) + two BW-shifts:
//  (a) qk folded into prep (reads f32 x directly, round-5-proven),
//  (b) softmax writes only attnB bf16; gemm1 expands attnB->attnF f32
//      interleaved in its K-loop (store chunk tt-2, load chunk tt-1;
//      vmcnt(9) boundaries) so the 134MB write rides gemm1's idle BW.
// ---------------------------------------------------------------------------

typedef __attribute__((ext_vector_type(8))) __bf16 bf16x8;
typedef __attribute__((ext_vector_type(4))) __bf16 bf16x4;
typedef __attribute__((ext_vector_type(4))) float  f32x4;
typedef unsigned int u32;

#define GLB_CAST(p) ((const __attribute__((address_space(1))) u32*)(p))
#define LDS_CAST(p) ((__attribute__((address_space(3))) u32*)(p))

#define S_BARRIER() { __builtin_amdgcn_s_barrier(); __builtin_amdgcn_sched_barrier(0); }
#define LGKM0()     { asm volatile("s_waitcnt lgkmcnt(0)" ::: "memory"); __builtin_amdgcn_sched_barrier(0); }
#define VMCNT9()    { asm volatile("s_waitcnt vmcnt(9)" ::: "memory"); __builtin_amdgcn_sched_barrier(0); }
#define VMCNT8()    { asm volatile("s_waitcnt vmcnt(8)" ::: "memory"); __builtin_amdgcn_sched_barrier(0); }
#define VMCNT0()    { asm volatile("s_waitcnt vmcnt(0)" ::: "memory"); __builtin_amdgcn_sched_barrier(0); }

static constexpr int    Bn   = 8;
static constexpr int    S    = 2048;
static constexpr int    Dd   = 1024;
static constexpr int    Mtot = Bn * S;            // 16384
static constexpr size_t OUT0 = (size_t)Bn * S * Dd;

// workspace layout (bytes)
static constexpr size_t OFF_XBF  = 0;                                  // [16384][1024] bf16
static constexpr size_t OFF_WVT  = OFF_XBF + (size_t)Mtot * Dd * 2;    // [1024][1024] bf16 (Wv^T)
static constexpr size_t OFF_Q    = OFF_WVT + (size_t)Dd * Dd * 2;      // [16384][8] f32
static constexpr size_t OFF_K    = OFF_Q   + (size_t)Mtot * 8 * 4;     // [16384][8] f32
static constexpr size_t OFF_VT   = OFF_K   + (size_t)Mtot * 8 * 4;     // [8][1024][2048] bf16
static constexpr size_t OFF_ATTB = OFF_VT  + (size_t)Bn * Dd * S * 2;  // [8][2048][2048] bf16
static constexpr size_t WS_NEED  = OFF_ATTB + (size_t)Bn * S * S * 2;  // ~137 MB

// ---------------------------------------------------------------------------
// prep: blocks [0,256): q/k projection from f32 x, Wq, Wk (bf16 MFMA);
//       [256,512): Wv -> Wv^T bf16 ; [512,4608): x f32 -> bf16.
// ---------------------------------------------------------------------------
__global__ __launch_bounds__(256) void prep_kernel(
    const float* __restrict__ x, const float* __restrict__ Wq,
    const float* __restrict__ Wk, const float* __restrict__ Wv,
    const float* __restrict__ bq, const float* __restrict__ bk,
    __bf16* __restrict__ xbf, __bf16* __restrict__ wvt,
    float* __restrict__ qb, float* __restrict__ kb)
{
    __shared__ float lt[64][65];
    int bid = blockIdx.x, t = threadIdx.x;
    if (bid < 256) {
        int l = t & 63, w = t >> 6;
        int mbase = (bid * 4 + w) * 16;
        int n = l & 15;
        int dbase = (l >> 4) << 3;
        const float* xr = x + (size_t)(mbase + n) * 1024 + dbase;
        const float* wcol = (n < 8) ? (Wq + n) : (Wk + (n & 7));
        f32x4 acc = {0.f, 0.f, 0.f, 0.f};
        #pragma unroll 4
        for (int kk = 0; kk < 1024; kk += 32) {
            f32x4 a0 = *(const f32x4*)(xr + kk);
            f32x4 a1 = *(const f32x4*)(xr + kk + 4);
            bf16x8 a, b;
            #pragma unroll
            for (int c = 0; c < 4; ++c) { a[c] = (__bf16)a0[c]; a[4 + c] = (__bf16)a1[c]; }
            #pragma unroll
            for (int u = 0; u < 8; ++u) b[u] = (__bf16)wcol[(size_t)(dbase + kk + u) * 8];
            acc = __builtin_amdgcn_mfma_f32_16x16x32_bf16(a, b, acc, 0, 0, 0);
        }
        float bias = (n < 8) ? bq[n] : bk[n & 7];
        #pragma unroll
        for (int r = 0; r < 4; ++r) {
            int m = mbase + ((l >> 4) << 2) + r;
            float v = acc[r] + bias;
            if (n < 8) qb[m * 8 + n] = v;
            else       kb[m * 8 + (n & 7)] = v;
        }
    } else if (bid < 512) {
        int tile = bid - 256;
        int tr = tile >> 4, tc = tile & 15;
        int r0 = t >> 6, c = t & 63;
        #pragma unroll
        for (int i = 0; i < 16; ++i) {
            int row = i * 4 + r0;
            lt[row][c] = Wv[(size_t)(tr * 64 + row) * 1024 + tc * 64 + c];
        }
        __syncthreads();
        #pragma unroll
        for (int i = 0; i < 16; ++i) {
            int er = i * 4 + r0;
            wvt[(size_t)(tc * 64 + er) * 1024 + tr * 64 + c] = (__bf16)lt[c][er];
        }
    } else {
        int bid2 = bid - 512;
        #pragma unroll
        for (int i = 0; i < 4; ++i) {
            size_t idx4 = (size_t)i * 1048576 + (size_t)bid2 * 256 + t;
            f32x4 v = ((const f32x4*)x)[idx4];
            bf16x4 o;
            #pragma unroll
            for (int c = 0; c < 4; ++c) o[c] = (__bf16)v[c];
            ((bf16x4*)xbf)[idx4] = o;
        }
    }
}

// ---------------------------------------------------------------------------
// fused gemm0 || softmax. Grid 1536 x 256 threads.
// Segments of 256 blocks: 0=G,1=S,2=G,3=S,4=G,5=G (1024 gemm tiles, 512 sm
// chunks). gemm0: m97-class C[128(s)x128(e)], BK=64, 4 waves, single-buffer
// 32KB LDS, XOR swizzle; writes vt[b][e][s] bf16 + bias.
// softmax: round-3 structure but writes ONLY attnB bf16 (attnF deferred).
// ---------------------------------------------------------------------------
__global__ __launch_bounds__(256) void fused_gs_kernel(
    const __bf16* __restrict__ xbf, const __bf16* __restrict__ wvt,
    const float* __restrict__ bv,
    const float* __restrict__ qb, const float* __restrict__ kb,
    __bf16* __restrict__ vtOut, __bf16* __restrict__ attnB)
{
    __shared__ __align__(1024) char smem[32768];
    __shared__ float redm[4], reds[4];
    int bid = blockIdx.x, t = threadIdx.x;
    int seg = bid >> 8;
    int gid = -1, sid = -1;
    if (seg == 0) gid = bid;
    else if (seg == 1) sid = bid - 256;
    else if (seg == 2) gid = bid - 256;
    else if (seg == 3) sid = bid - 512;
    else gid = bid - 512;                        // segs 4,5 -> gid 512..1023

    if (sid < 0) {
        // ================= gemm0 (m97-class) =================
        int g = ((gid & 7) << 7) | (gid >> 3);   // bijective XCD swizzle (1024)
        int mblk = g >> 3, nblk = g & 7;         // 128 x 8
        int l = t & 63, wid = t >> 6;
        int wmr = wid >> 1, wnc = wid & 1;       // 2(M) x 2(N) waves
        int lr = l & 15, lk = l >> 4;

        int srow = t >> 3;                       // 0..31
        int ssl  = (t & 7) ^ (srow & 7);
        const __bf16* gA = xbf + (size_t)(mblk * 128 + srow) * 1024 + ssl * 8;
        const __bf16* gB = wvt + (size_t)(nblk * 128 + srow) * 1024 + ssl * 8;

        int s0 = (lk ^ (lr & 7)) << 3;
        int s1 = ((lk ^ 4) ^ (lr & 7)) << 3;
        int offA0 = (wmr * 64 + lr) * 64 + s0;
        int offA1 = (wmr * 64 + lr) * 64 + s1;
        int offB0 = (wnc * 64 + lr) * 64 + s0;
        int offB1 = (wnc * 64 + lr) * 64 + s1;

        f32x4 acc[4][4] = {};

        for (int tt = 0; tt < 16; ++tt) {
            int kk = tt * 64;
            #pragma unroll
            for (int c = 0; c < 4; ++c) {
                __builtin_amdgcn_global_load_lds(
                    GLB_CAST(gA + (size_t)c * 32 * 1024 + kk),
                    LDS_CAST(smem + c * 4096 + wid * 1024), 16, 0, 0);
                __builtin_amdgcn_global_load_lds(
                    GLB_CAST(gB + (size_t)c * 32 * 1024 + kk),
                    LDS_CAST(smem + 16384 + c * 4096 + wid * 1024), 16, 0, 0);
            }
            __syncthreads();
            const __bf16* As = (const __bf16*)smem;
            const __bf16* Bs = (const __bf16*)(smem + 16384);
            bf16x8 af[4], bfr[4];
            #pragma unroll
            for (int i = 0; i < 4; ++i) af[i]  = *(const bf16x8*)(As + offA0 + i * 1024);
            #pragma unroll
            for (int j = 0; j < 4; ++j) bfr[j] = *(const bf16x8*)(Bs + offB0 + j * 1024);
            #pragma unroll
            for (int i = 0; i < 4; ++i)
                #pragma unroll
                for (int j = 0; j < 4; ++j)
                    acc[i][j] = __builtin_amdgcn_mfma_f32_16x16x32_bf16(af[i], bfr[j], acc[i][j], 0, 0, 0);
            #pragma unroll
            for (int i = 0; i < 4; ++i) af[i]  = *(const bf16x8*)(As + offA1 + i * 1024);
            #pragma unroll
            for (int j = 0; j < 4; ++j) bfr[j] = *(const bf16x8*)(Bs + offB1 + j * 1024);
            #pragma unroll
            for (int i = 0; i < 4; ++i)
                #pragma unroll
                for (int j = 0; j < 4; ++j)
                    acc[i][j] = __builtin_amdgcn_mfma_f32_16x16x32_bf16(af[i], bfr[j], acc[i][j], 0, 0, 0);
            __syncthreads();
        }

        #pragma unroll
        for (int j = 0; j < 4; ++j) {
            int e = (nblk << 7) + wnc * 64 + j * 16 + lr;
            float bias = bv[e];
            #pragma unroll
            for (int i = 0; i < 4; ++i) {
                int m0 = (mblk << 7) + wmr * 64 + i * 16 + (lk << 2);
                int b = m0 >> 11, sA = m0 & 2047;
                bf16x4 o;
                #pragma unroll
                for (int r = 0; r < 4; ++r) o[r] = (__bf16)(acc[i][j][r] + bias);
                *(bf16x4*)&vtOut[(((size_t)(b << 10) + e) << 11) + sA] = o;
            }
        }
    } else {
        // ================= softmax (attnB only) =================
        int b = sid >> 6, chunk = sid & 63;
        int l = t & 63, w = t >> 6;
        float kr[8][8];
        const float* kbb = kb + ((size_t)b << 14);
        #pragma unroll
        for (int jj = 0; jj < 8; ++jj) {
            f32x4 v0 = *(const f32x4*)(kbb + (size_t)(t * 8 + jj) * 8);
            f32x4 v1 = *(const f32x4*)(kbb + (size_t)(t * 8 + jj) * 8 + 4);
            #pragma unroll
            for (int c = 0; c < 4; ++c) { kr[jj][c] = v0[c]; kr[jj][4 + c] = v1[c]; }
        }
        const float* qrow = qb + ((size_t)b << 14);
        for (int ii = 0; ii < 32; ++ii) {
            int i = (chunk << 5) + ii;
            f32x4 q0 = *(const f32x4*)(qrow + (size_t)i * 8);
            f32x4 q1 = *(const f32x4*)(qrow + (size_t)i * 8 + 4);
            float e[8];
            #pragma unroll
            for (int jj = 0; jj < 8; ++jj) {
                float s = q0[0] * kr[jj][0];
                s = fmaf(q0[1], kr[jj][1], s);
                s = fmaf(q0[2], kr[jj][2], s);
                s = fmaf(q0[3], kr[jj][3], s);
                s = fmaf(q1[0], kr[jj][4], s);
                s = fmaf(q1[1], kr[jj][5], s);
                s = fmaf(q1[2], kr[jj][6], s);
                s = fmaf(q1[3], kr[jj][7], s);
                e[jj] = s;
            }
            float mx = e[0];
            #pragma unroll
            for (int jj = 1; jj < 8; ++jj) mx = fmaxf(mx, e[jj]);
            #pragma unroll
            for (int d = 1; d < 64; d <<= 1) mx = fmaxf(mx, __shfl_xor(mx, d));
            if (l == 0) redm[w] = mx;
            __syncthreads();
            mx = fmaxf(fmaxf(redm[0], redm[1]), fmaxf(redm[2], redm[3]));
            float p[8], sum = 0.f;
            #pragma unroll
            for (int jj = 0; jj < 8; ++jj) { p[jj] = __expf(e[jj] - mx); sum += p[jj]; }
            #pragma unroll
            for (int d = 1; d < 64; d <<= 1) sum += __shfl_xor(sum, d);
            if (l == 0) reds[w] = sum;
            __syncthreads();
            float T = (reds[0] + reds[1]) + (reds[2] + reds[3]);
            float inv = 1.0f / T;
            size_t off = (((size_t)b << 11) + i) * 2048 + (size_t)t * 8;
            bf16x8 ob;
            #pragma unroll
            for (int c = 0; c < 4; ++c) {
                ob[c] = (__bf16)(p[c] * inv); ob[4 + c] = (__bf16)(p[4 + c] * inv);
            }
            *(bf16x8*)(attnB + off) = ob;
        }
    }
}

// ---------------------------------------------------------------------------
// gemm1 (8-phase) + interleaved attnB->attnF f32 expansion.
// Each block owns attnF rows [bb, mblk*256+nblk*64 .. +64) (unique tiling of
// all 16384 rows); per K-iter tt: store chunk tt-2 (in pv), load chunk tt-1.
// vmcnt boundaries: tt==0 -> 8 (no copy ops yet), tt>=1 -> 9 (8 staging +
// 1 copy-load; the 2 copy-stores are a full iteration old). Drain -> 0.
// ---------------------------------------------------------------------------
__device__ __forceinline__ void g1_stageA(const __bf16* Ab, char* smem,
    int slot, int kk, int c, int rowin, int sl8, int wid)
{
    __builtin_amdgcn_global_load_lds(
        GLB_CAST(Ab + (size_t)(c * 64 + rowin) * 2048 + kk + sl8 * 8),
        LDS_CAST(smem + slot * 65536 + c * 8192 + wid * 1024), 16, 0, 0);
}
__device__ __forceinline__ void g1_stageB(const __bf16* Bb, char* smem,
    int slot, int kk, int c, int rowin, int sl8, int wid)
{
    __builtin_amdgcn_global_load_lds(
        GLB_CAST(Bb + (size_t)(c * 64 + rowin) * 2048 + kk + sl8 * 8),
        LDS_CAST(smem + slot * 65536 + 32768 + c * 8192 + wid * 1024), 16, 0, 0);
}

__global__ __launch_bounds__(512, 2) void gemm1_kernel(
    const __bf16* __restrict__ A, const __bf16* __restrict__ Bt,
    float* __restrict__ outF, float* __restrict__ attnF)
{
    constexpr int NT = 32;
    __shared__ __align__(1024) char smem[131072];

    int bid = blockIdx.x;
    int wg = ((bid & 7) << 5) | (bid >> 3);     // bijective XCD swizzle (nwg=256)
    int t = threadIdx.x, l = t & 63;
    int wid = t >> 6;
    int wmr = wid >> 2, wnc = wid & 3;

    int bb = wg >> 5; int r = wg & 31;          // one batch per XCD
    int mblk = r >> 2, nblk = r & 3;
    const __bf16* Ab = A + (size_t)bb * S * S + (size_t)mblk * 256 * 2048;
    const __bf16* Bb = Bt + (size_t)bb * Dd * S + (size_t)nblk * 256 * 2048;

    int rowin = t >> 3;
    int sl8 = (t & 7) ^ (rowin & 7);
    int lr = l & 15, lk = l >> 4;

    // attnF copy-role: row slice nblk*64 + (t>>3), col chunk (t&7)*8
    int crow = nblk * 64 + (t >> 3);
    int ccol = (t & 7) * 8;
    const __bf16* cpSrc = Ab + (size_t)crow * 2048 + ccol;
    float* cpDst = attnF + ((size_t)bb << 22) + ((size_t)(mblk * 256 + crow) << 11) + ccol;
    bf16x8 pv;

    f32x4 acc[8][4] = {};

    #pragma unroll
    for (int c = 0; c < 4; ++c) {
        g1_stageA(Ab, smem, 0, 0, c, rowin, sl8, wid);
        g1_stageB(Bb, smem, 0, 0, c, rowin, sl8, wid);
    }
    #pragma unroll
    for (int c = 0; c < 4; ++c) {
        g1_stageA(Ab, smem, 1, 64, c, rowin, sl8, wid);
        g1_stageB(Bb, smem, 1, 64, c, rowin, sl8, wid);
    }
    VMCNT8();
    S_BARRIER();

    for (int tt = 0; tt < NT; ++tt) {
        int s = tt & 1;
        const __bf16* Asl = (const __bf16*)(smem + s * 65536);
        const __bf16* Bsl = (const __bf16*)(smem + s * 65536 + 32768);
        bool pf = (tt + 2 < NT);
        int kk2 = (tt + 2) * 64;

        // ---- interleaved attnF copy: store chunk tt-2, load chunk tt-1
        if (tt >= 2) {
            f32x4 c0, c1;
            #pragma unroll
            for (int c = 0; c < 4; ++c) { c0[c] = (float)pv[c]; c1[c] = (float)pv[4 + c]; }
            *(f32x4*)(cpDst + (tt - 2) * 64) = c0;
            *(f32x4*)(cpDst + (tt - 2) * 64 + 4) = c1;
        }
        if (tt >= 1) {
            pv = *(const bf16x8*)(cpSrc + (tt - 1) * 64);
        }

        bf16x8 aLo[2][4], aHi[2][4], bLo[2][2], bHi[2][2];

        // ---- P0
        #pragma unroll
        for (int ks = 0; ks < 2; ++ks) {
            int sa = ks * 4 + lk;
            #pragma unroll
            for (int i = 0; i < 4; ++i) {
                int ra = wmr * 128 + i * 16 + lr;
                aLo[ks][i] = *(const bf16x8*)&Asl[ra * 64 + ((sa ^ (ra & 7)) << 3)];
            }
            #pragma unroll
            for (int j = 0; j < 2; ++j) {
                int rb = wnc * 64 + j * 16 + lr;
                bLo[ks][j] = *(const bf16x8*)&Bsl[rb * 64 + ((sa ^ (rb & 7)) << 3)];
            }
        }
        S_BARRIER(); LGKM0();
        __builtin_amdgcn_s_setprio(1);
        #pragma unroll
        for (int ks = 0; ks < 2; ++ks)
            #pragma unroll
            for (int i = 0; i < 4; ++i)
                #pragma unroll
                for (int j = 0; j < 2; ++j)
                    acc[i][j] = __builtin_amdgcn_mfma_f32_16x16x32_bf16(aLo[ks][i], bLo[ks][j], acc[i][j], 0, 0, 0);
        __builtin_amdgcn_s_setprio(0);
        S_BARRIER();

        // ---- P1
        #pragma unroll
        for (int ks = 0; ks < 2; ++ks) {
            int sa = ks * 4 + lk;
            #pragma unroll
            for (int j = 0; j < 2; ++j) {
                int rb = wnc * 64 + (j + 2) * 16 + lr;
                bHi[ks][j] = *(const bf16x8*)&Bsl[rb * 64 + ((sa ^ (rb & 7)) << 3)];
            }
        }
        if (pf) {
            g1_stageA(Ab, smem, s, kk2, 0, rowin, sl8, wid);
            g1_stageA(Ab, smem, s, kk2, 2, rowin, sl8, wid);
        }
        S_BARRIER(); LGKM0();
        __builtin_amdgcn_s_setprio(1);
        #pragma unroll
        for (int ks = 0; ks < 2; ++ks)
            #pragma unroll
            for (int i = 0; i < 4; ++i)
                #pragma unroll
                for (int j = 0; j < 2; ++j)
                    acc[i][2 + j] = __builtin_amdgcn_mfma_f32_16x16x32_bf16(aLo[ks][i], bHi[ks][j], acc[i][2 + j], 0, 0, 0);
        __builtin_amdgcn_s_setprio(0);
        S_BARRIER();

        // ---- P2
        #pragma unroll
        for (int ks = 0; ks < 2; ++ks) {
            int sa = ks * 4 + lk;
            #pragma unroll
            for (int i = 0; i < 4; ++i) {
                int ra = wmr * 128 + (i + 4) * 16 + lr;
                aHi[ks][i] = *(const bf16x8*)&Asl[ra * 64 + ((sa ^ (ra & 7)) << 3)];
            }
        }
        if (pf) {
            #pragma unroll
            for (int c = 0; c < 4; ++c)
                g1_stageB(Bb, smem, s, kk2, c, rowin, sl8, wid);
        }
        S_BARRIER(); LGKM0();
        __builtin_amdgcn_s_setprio(1);
        #pragma unroll
        for (int ks = 0; ks < 2; ++ks)
            #pragma unroll
            for (int i = 0; i < 4; ++i)
                #pragma unroll
                for (int j = 0; j < 2; ++j)
                    acc[4 + i][2 + j] = __builtin_amdgcn_mfma_f32_16x16x32_bf16(aHi[ks][i], bHi[ks][j], acc[4 + i][2 + j], 0, 0, 0);
        __builtin_amdgcn_s_setprio(0);
        S_BARRIER();

        // ---- P3
        if (pf) {
            g1_stageA(Ab, smem, s, kk2, 1, rowin, sl8, wid);
            g1_stageA(Ab, smem, s, kk2, 3, rowin, sl8, wid);
        }
        S_BARRIER();
        __builtin_amdgcn_s_setprio(1);
        #pragma unroll
        for (int ks = 0; ks < 2; ++ks)
            #pragma unroll
            for (int i = 0; i < 4; ++i)
                #pragma unroll
                for (int j = 0; j < 2; ++j)
                    acc[4 + i][j] = __builtin_amdgcn_mfma_f32_16x16x32_bf16(aHi[ks][i], bLo[ks][j], acc[4 + i][j], 0, 0, 0);
        __builtin_amdgcn_s_setprio(0);

        if (tt == NT - 1) break;
        S_BARRIER();
        if (pf) {
            if (tt == 0) { VMCNT8(); } else { VMCNT9(); }
        } else {
            VMCNT0();
        }
        S_BARRIER();
    }

    // ---- finish attnF chunks NT-2 (in pv) and NT-1
    {
        f32x4 c0, c1;
        #pragma unroll
        for (int c = 0; c < 4; ++c) { c0[c] = (float)pv[c]; c1[c] = (float)pv[4 + c]; }
        *(f32x4*)(cpDst + (NT - 2) * 64) = c0;
        *(f32x4*)(cpDst + (NT - 2) * 64 + 4) = c1;
        bf16x8 lastv = *(const bf16x8*)(cpSrc + (NT - 1) * 64);
        #pragma unroll
        for (int c = 0; c < 4; ++c) { c0[c] = (float)lastv[c]; c1[c] = (float)lastv[4 + c]; }
        *(f32x4*)(cpDst + (NT - 1) * 64) = c0;
        *(f32x4*)(cpDst + (NT - 1) * 64 + 4) = c1;
    }

    float* ob = outF + (size_t)bb * S * Dd;
    #pragma unroll
    for (int i = 0; i < 8; ++i) {
        int m0 = (mblk << 8) + wmr * 128 + i * 16 + (lk << 2);
        #pragma unroll
        for (int j = 0; j < 4; ++j) {
            int e = (nblk << 8) + wnc * 64 + j * 16 + lr;
            #pragma unroll
            for (int r = 0; r < 4; ++r)
                ob[(size_t)(m0 + r) * 1024 + e] = acc[i][j][r];
        }
    }
}

// ---------------------------------------------------------------------------
extern "C" void kernel_launch(void* const* d_in, const int* in_sizes, int n_in,
                              void* d_out, int out_size, void* d_ws, size_t ws_size,
                              hipStream_t stream)
{
    const float* x  = (const float*)d_in[0];
    const float* Wq = (const float*)d_in[1];
    const float* bq = (const float*)d_in[2];
    const float* Wk = (const float*)d_in[3];
    const float* bk = (const float*)d_in[4];
    const float* Wv = (const float*)d_in[5];
    const float* bv = (const float*)d_in[6];

    float* outp  = (float*)d_out;
    float* attnF = outp + OUT0;

    if (ws_size < WS_NEED) return;
    char* ws = (char*)d_ws;
    __bf16* xbf   = (__bf16*)(ws + OFF_XBF);
    __bf16* wvt   = (__bf16*)(ws + OFF_WVT);
    float*  qbuf  = (float*)(ws + OFF_Q);
    float*  kbuf  = (float*)(ws + OFF_K);
    __bf16* vt    = (__bf16*)(ws + OFF_VT);
    __bf16* attnB = (__bf16*)(ws + OFF_ATTB);

    prep_kernel<<<4608, 256, 0, stream>>>(x, Wq, Wk, Wv, bq, bk, xbf, wvt, qbuf, kbuf);
    fused_gs_kernel<<<1536, 256, 0, stream>>>(xbf, wvt, bv, qbuf, kbuf, vt, attnB);
    gemm1_kernel<<<256, 512, 0, stream>>>(attnB, vt, outp, attnF);
}